// Round 2
// baseline (222.844 us; speedup 1.0000x reference)
//
#include <hip/hip_runtime.h>

// DeformationTrackerBiFlowModel — autoregressive Dense-feedback recurrence.
// B=65536 independent rows, each strictly serial over T=100 steps.
// One thread per batch row; 65536 threads = 1024 waves = 1 wave/SIMD, so
// latency hiding is register-level prefetch (distance-2 double buffer).
// tanh via native v_exp_f32/v_rcp_f32 (stable form, t<=1, ~8 VALU) instead of
// OCML tanhf (~20+ VALU) — tanh was ~3/4 of the serial VALU stream.

constexpr int Bn  = 65536;
constexpr int Tn  = 100;
constexpr int HID = 12;

__device__ __forceinline__ float fast_tanh(float a) {
    // tanh(a) = sign(a) * (1 - e^{-2|a|}) / (1 + e^{-2|a|}),  e^{-2|a|} <= 1
    const float ax = __builtin_fabsf(a);
    const float t  = __builtin_amdgcn_exp2f(ax * -2.885390081777927f); // -2*log2(e)
    const float r  = (1.0f - t) * __builtin_amdgcn_rcpf(1.0f + t);
    return __builtin_copysignf(r, a);
}

__global__ __launch_bounds__(256, 1) void deform_kernel(
    const float* __restrict__ cp,    // (B,T,2)
    const float* __restrict__ fin,   // (B,T,3)
    const float* __restrict__ Wr,    // (5,12) row-major
    const float* __restrict__ br_,   // (12)
    const float* __restrict__ Wo,    // (14,2) row-major
    const float* __restrict__ bo_,   // (2)
    float* __restrict__ out)         // (B,T,2)
{
    const int b = blockIdx.x * blockDim.x + threadIdx.x;

    // Wave-uniform weight loads with constant offsets -> scalar broadcasts.
    float w[5][HID];
    #pragma unroll
    for (int i = 0; i < 5; ++i)
        #pragma unroll
        for (int j = 0; j < HID; ++j)
            w[i][j] = Wr[i * HID + j];

    float br[HID];
    #pragma unroll
    for (int j = 0; j < HID; ++j) br[j] = br_[j];

    float woh[HID][2];
    #pragma unroll
    for (int j = 0; j < HID; ++j) {
        woh[j][0] = Wo[(2 + j) * 2 + 0];
        woh[j][1] = Wo[(2 + j) * 2 + 1];
    }
    const float wo00 = Wo[0], wo01 = Wo[1];   // row 0: cp0.x weights
    const float wo10 = Wo[2], wo11 = Wo[3];   // row 1: cp0.y weights
    const float bo0 = bo_[0], bo1 = bo_[1];

    const float cp0x = cp[(size_t)b * Tn * 2 + 0];
    const float cp0y = cp[(size_t)b * Tn * 2 + 1];

    // cp0 contribution to the output is loop-invariant.
    const float oc0 = bo0 + cp0x * wo00 + cp0y * wo10;
    const float oc1 = bo1 + cp0x * wo01 + cp0y * wo11;

    float px = cp0x, py = cp0y;  // fed-back output

    // Per-batch rows: fin row = 300 floats (1200 B, 16B-aligned),
    // out row = 200 floats (800 B, 16B-aligned).
    const float4* __restrict__ fp = reinterpret_cast<const float4*>(fin + (size_t)b * Tn * 3);
    float4* __restrict__ op = reinterpret_cast<float4*>(out + (size_t)b * Tn * 2);

    // 25 chunks of 4 timesteps; 3 float4 loads per chunk; prefetch distance 2.
    float4 cur0 = fp[0], cur1 = fp[1], cur2 = fp[2];
    float4 nxt0 = fp[3], nxt1 = fp[4], nxt2 = fp[5];

    #pragma unroll 1
    for (int c = 0; c < 25; ++c) {
        const int cpre = (c + 2 < 25) ? (c + 2) : 24;
        const float4 pf0 = fp[cpre * 3 + 0];
        const float4 pf1 = fp[cpre * 3 + 1];
        const float4 pf2 = fp[cpre * 3 + 2];

        const float f[12] = {cur0.x, cur0.y, cur0.z, cur0.w,
                             cur1.x, cur1.y, cur1.z, cur1.w,
                             cur2.x, cur2.y, cur2.z, cur2.w};
        float o[8];
        #pragma unroll
        for (int s = 0; s < 4; ++s) {
            const float fx = f[s * 3 + 0];
            const float fy = f[s * 3 + 1];
            const float fz = f[s * 3 + 2];
            float o0 = oc0, o1 = oc1;
            #pragma unroll
            for (int j = 0; j < HID; ++j) {
                const float a = br[j] + px * w[0][j] + py * w[1][j]
                              + fx * w[2][j] + fy * w[3][j] + fz * w[4][j];
                const float h = fast_tanh(a);
                o0 += h * woh[j][0];
                o1 += h * woh[j][1];
            }
            o[s * 2 + 0] = o0;
            o[s * 2 + 1] = o1;
            px = o0; py = o1;
        }

        op[c * 2 + 0] = make_float4(o[0], o[1], o[2], o[3]);
        op[c * 2 + 1] = make_float4(o[4], o[5], o[6], o[7]);

        cur0 = nxt0; cur1 = nxt1; cur2 = nxt2;
        nxt0 = pf0;  nxt1 = pf1;  nxt2 = pf2;
    }
}

extern "C" void kernel_launch(void* const* d_in, const int* in_sizes, int n_in,
                              void* d_out, int out_size, void* d_ws, size_t ws_size,
                              hipStream_t stream) {
    const float* cp  = (const float*)d_in[0];  // control_point_input
    const float* fin = (const float*)d_in[1];  // finger_input
    const float* Wr  = (const float*)d_in[2];  // W_rnn
    // d_in[3] = U_rnn — mathematically inert (h0 == 0 each step), unused.
    const float* br  = (const float*)d_in[4];  // b_rnn
    const float* Wo  = (const float*)d_in[5];  // W_out
    const float* bo  = (const float*)d_in[6];  // b_out
    float* out = (float*)d_out;

    deform_kernel<<<dim3(Bn / 256), dim3(256), 0, stream>>>(cp, fin, Wr, br, Wo, bo, out);
}

// Round 3
// 210.314 us; speedup vs baseline: 1.0596x; 1.0596x over previous
//
#include <hip/hip_runtime.h>

// DeformationTrackerBiFlowModel — autoregressive Dense-feedback recurrence.
// B=65536 rows, strictly serial T=100 steps per row.
//
// R2 restructure: 4 lanes per row (3 hidden units each) -> 262144 threads =
// 4096 waves = 4 waves/SIMD (was 1), hiding the dep-chain stalls that left
// VALUBusy at 37%. Partial outputs combined across the 4-lane group with a
// DPP quad_perm butterfly (VALU-only, no LDS). tanh = 1 - 2/(1+e^{2a})
// (exact; correct at +/-inf via rcp(inf)=0) = 5 VALU ops incl 2 trans.

constexpr int Bn  = 65536;
constexpr int Tn  = 100;
constexpr int HID = 12;
constexpr int LPR = 4;   // lanes per row
constexpr int UPL = 3;   // hidden units per lane

template <int CTRL>
__device__ __forceinline__ float dpp_mov(float x) {
    return __builtin_bit_cast(float,
        __builtin_amdgcn_mov_dpp(__builtin_bit_cast(int, x), CTRL, 0xF, 0xF, true));
}

__device__ __forceinline__ float fast_tanh(float a) {
    // tanh(a) = 1 - 2/(1 + e^{2a})
    const float t = __builtin_amdgcn_exp2f(a * 2.885390081777927f); // 2*log2(e)
    return __builtin_fmaf(-2.0f, __builtin_amdgcn_rcpf(1.0f + t), 1.0f);
}

__global__ __launch_bounds__(256, 4) void deform_kernel(
    const float* __restrict__ cp,    // (B,T,2)
    const float* __restrict__ fin,   // (B,T,3)
    const float* __restrict__ Wr,    // (5,12) row-major
    const float* __restrict__ br_,   // (12)
    const float* __restrict__ Wo,    // (14,2) row-major
    const float* __restrict__ bo_,   // (2)
    float* __restrict__ out)         // (B,T,2)
{
    const int tid = blockIdx.x * blockDim.x + threadIdx.x;
    const int row = tid >> 2;     // batch row
    const int q   = tid & 3;      // sub-lane within the 4-lane group
    const int j0  = q * UPL;      // first hidden unit owned by this lane

    // Per-lane slice of the weights (q-dependent -> VGPRs).
    float w0[UPL], w1[UPL], w2[UPL], w3[UPL], w4[UPL];
    float brv[UPL], wo0[UPL], wo1[UPL];
    #pragma unroll
    for (int u = 0; u < UPL; ++u) {
        const int j = j0 + u;
        w0[u] = Wr[0 * HID + j];
        w1[u] = Wr[1 * HID + j];
        w2[u] = Wr[2 * HID + j];
        w3[u] = Wr[3 * HID + j];
        w4[u] = Wr[4 * HID + j];
        brv[u] = br_[j];
        wo0[u] = Wo[(2 + j) * 2 + 0];
        wo1[u] = Wo[(2 + j) * 2 + 1];
    }
    // Wave-uniform scalars.
    const float wo00 = Wo[0], wo01 = Wo[1];
    const float wo10 = Wo[2], wo11 = Wo[3];
    const float bo0 = bo_[0], bo1 = bo_[1];

    const float cp0x = cp[(size_t)row * Tn * 2 + 0];
    const float cp0y = cp[(size_t)row * Tn * 2 + 1];

    // cp0 contribution to the output is loop-invariant.
    const float oc0 = bo0 + cp0x * wo00 + cp0y * wo10;
    const float oc1 = bo1 + cp0x * wo01 + cp0y * wo11;

    float px = cp0x, py = cp0y;  // fed-back output (identical across the group)

    // fin row: 300 floats (1200 B, float4-aligned). All 4 lanes of a group
    // load the same addresses -> coalescer broadcast, no extra HBM traffic.
    const float4* __restrict__ fp = reinterpret_cast<const float4*>(fin + (size_t)row * Tn * 3);
    float2* __restrict__ op = reinterpret_cast<float2*>(out + (size_t)row * Tn * 2);

    // 25 chunks of 4 timesteps; 3 float4 loads per chunk; prefetch distance 2.
    float4 cur0 = fp[0], cur1 = fp[1], cur2 = fp[2];
    float4 nxt0 = fp[3], nxt1 = fp[4], nxt2 = fp[5];

    #pragma unroll 1
    for (int c = 0; c < 25; ++c) {
        const int cpre = (c + 2 < 25) ? (c + 2) : 24;
        const float4 pf0 = fp[cpre * 3 + 0];
        const float4 pf1 = fp[cpre * 3 + 1];
        const float4 pf2 = fp[cpre * 3 + 2];

        const float f[12] = {cur0.x, cur0.y, cur0.z, cur0.w,
                             cur1.x, cur1.y, cur1.z, cur1.w,
                             cur2.x, cur2.y, cur2.z, cur2.w};

        float so0 = 0.0f, so1 = 0.0f;  // this lane's step-q output of the chunk
        #pragma unroll
        for (int s = 0; s < 4; ++s) {
            const float fx = f[s * 3 + 0];
            const float fy = f[s * 3 + 1];
            const float fz = f[s * 3 + 2];
            float o0p = 0.0f, o1p = 0.0f;
            #pragma unroll
            for (int u = 0; u < UPL; ++u) {
                float a = brv[u];
                a = __builtin_fmaf(px, w0[u], a);
                a = __builtin_fmaf(py, w1[u], a);
                a = __builtin_fmaf(fx, w2[u], a);
                a = __builtin_fmaf(fy, w3[u], a);
                a = __builtin_fmaf(fz, w4[u], a);
                const float h = fast_tanh(a);
                o0p = __builtin_fmaf(h, wo0[u], o0p);
                o1p = __builtin_fmaf(h, wo1[u], o1p);
            }
            // 4-lane butterfly (quad_perm xor1 then xor2); all lanes end with
            // the bitwise-identical full sum.
            o0p += dpp_mov<0xB1>(o0p);
            o1p += dpp_mov<0xB1>(o1p);
            o0p += dpp_mov<0x4E>(o0p);
            o1p += dpp_mov<0x4E>(o1p);

            const float o0 = oc0 + o0p;
            const float o1 = oc1 + o1p;
            if (q == s) { so0 = o0; so1 = o1; }  // lane q archives step q
            px = o0; py = o1;
        }

        // Group stores 32 contiguous bytes: lane q -> step c*4+q.
        op[c * 4 + q] = make_float2(so0, so1);

        cur0 = nxt0; cur1 = nxt1; cur2 = nxt2;
        nxt0 = pf0;  nxt1 = pf1;  nxt2 = pf2;
    }
}

extern "C" void kernel_launch(void* const* d_in, const int* in_sizes, int n_in,
                              void* d_out, int out_size, void* d_ws, size_t ws_size,
                              hipStream_t stream) {
    const float* cp  = (const float*)d_in[0];  // control_point_input
    const float* fin = (const float*)d_in[1];  // finger_input
    const float* Wr  = (const float*)d_in[2];  // W_rnn
    // d_in[3] = U_rnn — mathematically inert (h0 == 0 each step), unused.
    const float* br  = (const float*)d_in[4];  // b_rnn
    const float* Wo  = (const float*)d_in[5];  // W_out
    const float* bo  = (const float*)d_in[6];  // b_out
    float* out = (float*)d_out;

    const int threads = Bn * LPR;  // 262144
    deform_kernel<<<dim3(threads / 256), dim3(256), 0, stream>>>(cp, fin, Wr, br, Wo, bo, out);
}

// Round 9
// 204.851 us; speedup vs baseline: 1.0878x; 1.0267x over previous
//
#include <hip/hip_runtime.h>

// DeformationTrackerBiFlowModel — autoregressive Dense-feedback recurrence.
// B=65536 rows, strictly serial T=100 steps per row.
//
// Structure: 4-lane group handles TWO rows (2g, 2g+1); lane q owns hidden
// units [3q,3q+3) of both. 131072 threads = 2048 waves = 2 waves/SIMD.
// R3 evidence: 4 phase-locked waves/SIMD stall together (VALUBusy 42%) ->
// TLP can't hide the carried chain; two independent rows per thread cover
// the chain stalls deterministically (row B issues while row A waits).
// tanh = 1 - 2/(1+e^{2a}) (exact at +/-inf, 5 ops, R2/R3-validated).
//
// Write clustering: post-butterfly ALL lanes hold every step's output, so
// lane q banks steps (8m+2q, 8m+2q+1) into a float4 and the group writes one
// fully-covered 64B window per row per 8 steps (was: 2x temporally-separated
// 32B half-line writes -> 1.67x WRITE_SIZE amplification, 87 vs 52 MB).

constexpr int Bn  = 65536;
constexpr int Tn  = 100;
constexpr int HID = 12;
constexpr int UPL = 3;   // hidden units per lane

template <int CTRL>
__device__ __forceinline__ float dpp_mov(float x) {
    return __builtin_bit_cast(float,
        __builtin_amdgcn_mov_dpp(__builtin_bit_cast(int, x), CTRL, 0xF, 0xF, true));
}

__device__ __forceinline__ float fast_tanh(float a) {
    // tanh(a) = 1 - 2/(1 + e^{2a}); rcp(inf)=0 handles saturation exactly.
    const float t = __builtin_amdgcn_exp2f(a * 2.885390081777927f); // 2*log2(e)
    return __builtin_fmaf(-2.0f, __builtin_amdgcn_rcpf(1.0f + t), 1.0f);
}

__global__ __launch_bounds__(256, 2) void deform_kernel(
    const float* __restrict__ cp,    // (B,T,2)
    const float* __restrict__ fin,   // (B,T,3)
    const float* __restrict__ Wr,    // (5,12) row-major
    const float* __restrict__ br_,   // (12)
    const float* __restrict__ Wo,    // (14,2) row-major
    const float* __restrict__ bo_,   // (2)
    float* __restrict__ out)         // (B,T,2)
{
    const int tid   = blockIdx.x * blockDim.x + threadIdx.x;
    const int group = tid >> 2;   // handles rows 2*group, 2*group+1
    const int q     = tid & 3;
    const int j0    = q * UPL;

    // Per-lane weight slice (shared by both rows).
    float w0[UPL], w1[UPL], w2[UPL], w3[UPL], w4[UPL];
    float brv[UPL], wo0[UPL], wo1[UPL];
    #pragma unroll
    for (int u = 0; u < UPL; ++u) {
        const int j = j0 + u;
        w0[u] = Wr[0 * HID + j];
        w1[u] = Wr[1 * HID + j];
        w2[u] = Wr[2 * HID + j];
        w3[u] = Wr[3 * HID + j];
        w4[u] = Wr[4 * HID + j];
        brv[u] = br_[j];
        wo0[u] = Wo[(2 + j) * 2 + 0];
        wo1[u] = Wo[(2 + j) * 2 + 1];
    }
    const float wo00 = Wo[0], wo01 = Wo[1];
    const float wo10 = Wo[2], wo11 = Wo[3];
    const float bo0 = bo_[0], bo1 = bo_[1];

    const int rowA = group * 2;
    const int rowB = rowA + 1;

    const float cpAx = cp[(size_t)rowA * Tn * 2 + 0];
    const float cpAy = cp[(size_t)rowA * Tn * 2 + 1];
    const float cpBx = cp[(size_t)rowB * Tn * 2 + 0];
    const float cpBy = cp[(size_t)rowB * Tn * 2 + 1];

    const float ocA0 = bo0 + cpAx * wo00 + cpAy * wo10;
    const float ocA1 = bo1 + cpAx * wo01 + cpAy * wo11;
    const float ocB0 = bo0 + cpBx * wo00 + cpBy * wo10;
    const float ocB1 = bo1 + cpBx * wo01 + cpBy * wo11;

    float pxA = cpAx, pyA = cpAy;
    float pxB = cpBx, pyB = cpBy;

    const float4* __restrict__ fpA = reinterpret_cast<const float4*>(fin + (size_t)rowA * Tn * 3);
    const float4* __restrict__ fpB = reinterpret_cast<const float4*>(fin + (size_t)rowB * Tn * 3);
    // float4 output view: 50 float4 per row (800 B, 16B-aligned).
    float4* __restrict__ o4A = reinterpret_cast<float4*>(out) + (size_t)rowA * 50;
    float4* __restrict__ o4B = reinterpret_cast<float4*>(out) + (size_t)rowB * 50;

    // Distance-2 prefetch, both rows.
    float4 cA0 = fpA[0], cA1 = fpA[1], cA2 = fpA[2];
    float4 nA0 = fpA[3], nA1 = fpA[4], nA2 = fpA[5];
    float4 cB0 = fpB[0], cB1 = fpB[1], cB2 = fpB[2];
    float4 nB0 = fpB[3], nB1 = fpB[4], nB2 = fpB[5];

    // Banked outputs: lane q accumulates steps (8m+2q, 8m+2q+1) of each
    // 8-step window as {x,y}={o0,o1}(even step), {z,w}=(odd step).
    float4 vA = make_float4(0.f, 0.f, 0.f, 0.f);
    float4 vB = make_float4(0.f, 0.f, 0.f, 0.f);

    #pragma unroll 1
    for (int c = 0; c < 25; ++c) {
        const int cpre = (c + 2 < 25) ? (c + 2) : 24;
        const float4 pA0 = fpA[cpre * 3 + 0];
        const float4 pA1 = fpA[cpre * 3 + 1];
        const float4 pA2 = fpA[cpre * 3 + 2];
        const float4 pB0 = fpB[cpre * 3 + 0];
        const float4 pB1 = fpB[cpre * 3 + 1];
        const float4 pB2 = fpB[cpre * 3 + 2];

        const float fA[12] = {cA0.x, cA0.y, cA0.z, cA0.w,
                              cA1.x, cA1.y, cA1.z, cA1.w,
                              cA2.x, cA2.y, cA2.z, cA2.w};
        const float fB[12] = {cB0.x, cB0.y, cB0.z, cB0.w,
                              cB1.x, cB1.y, cB1.z, cB1.w,
                              cB2.x, cB2.y, cB2.z, cB2.w};

        const int par = c & 1;            // half of the 8-step window
        #pragma unroll
        for (int s = 0; s < 4; ++s) {
            const float fAx = fA[s * 3 + 0], fAy = fA[s * 3 + 1], fAz = fA[s * 3 + 2];
            const float fBx = fB[s * 3 + 0], fBy = fB[s * 3 + 1], fBz = fB[s * 3 + 2];

            float oA0 = 0.0f, oA1 = 0.0f, oB0 = 0.0f, oB1 = 0.0f;
            #pragma unroll
            for (int u = 0; u < UPL; ++u) {
                // Feedback-independent part (schedulable early, off-chain):
                const float gA = __builtin_fmaf(fAz, w4[u],
                                 __builtin_fmaf(fAy, w3[u],
                                 __builtin_fmaf(fAx, w2[u], brv[u])));
                const float gB = __builtin_fmaf(fBz, w4[u],
                                 __builtin_fmaf(fBy, w3[u],
                                 __builtin_fmaf(fBx, w2[u], brv[u])));
                // Carried chain: 2 FMAs -> tanh. Rows A and B independent.
                const float aA = __builtin_fmaf(pyA, w1[u],
                                 __builtin_fmaf(pxA, w0[u], gA));
                const float aB = __builtin_fmaf(pyB, w1[u],
                                 __builtin_fmaf(pxB, w0[u], gB));
                const float hA = fast_tanh(aA);
                const float hB = fast_tanh(aB);
                oA0 = __builtin_fmaf(hA, wo0[u], oA0);
                oA1 = __builtin_fmaf(hA, wo1[u], oA1);
                oB0 = __builtin_fmaf(hB, wo0[u], oB0);
                oB1 = __builtin_fmaf(hB, wo1[u], oB1);
            }
            // 4-lane butterflies (quad_perm xor1, xor2) — A and B interleave.
            oA0 += dpp_mov<0xB1>(oA0);
            oA1 += dpp_mov<0xB1>(oA1);
            oB0 += dpp_mov<0xB1>(oB0);
            oB1 += dpp_mov<0xB1>(oB1);
            oA0 += dpp_mov<0x4E>(oA0);
            oA1 += dpp_mov<0x4E>(oA1);
            oB0 += dpp_mov<0x4E>(oB0);
            oB1 += dpp_mov<0x4E>(oB1);

            const float outA0 = ocA0 + oA0, outA1 = ocA1 + oA1;
            const float outB0 = ocB0 + oB0, outB1 = ocB1 + oB1;

            // Bank: window-step g = par*4+s; lane g>>1 takes slot g&1 (= s&1).
            if (q == 2 * par + (s >> 1)) {
                if ((s & 1) == 0) { vA.x = outA0; vA.y = outA1;
                                    vB.x = outB0; vB.y = outB1; }
                else              { vA.z = outA0; vA.w = outA1;
                                    vB.z = outB0; vB.w = outB1; }
            }
            pxA = outA0; pyA = outA1;
            pxB = outB0; pyB = outB1;
        }

        // End of an 8-step window: group writes 64B fully-covered per row.
        if (par) {
            const int m = c >> 1;            // window index 0..11
            o4A[m * 4 + q] = vA;
            o4B[m * 4 + q] = vB;
        }

        cA0 = nA0; cA1 = nA1; cA2 = nA2;
        nA0 = pA0; nA1 = pA1; nA2 = pA2;
        cB0 = nB0; cB1 = nB1; cB2 = nB2;
        nB0 = pB0; nB1 = pB1; nB2 = pB2;
    }

    // Tail: chunk 24 (steps 96..99) banked into lanes 0,1 (par=0, g=0..3).
    if (q < 2) {
        o4A[48 + q] = vA;
        o4B[48 + q] = vB;
    }
}

extern "C" void kernel_launch(void* const* d_in, const int* in_sizes, int n_in,
                              void* d_out, int out_size, void* d_ws, size_t ws_size,
                              hipStream_t stream) {
    const float* cp  = (const float*)d_in[0];  // control_point_input
    const float* fin = (const float*)d_in[1];  // finger_input
    const float* Wr  = (const float*)d_in[2];  // W_rnn
    // d_in[3] = U_rnn — mathematically inert (h0 == 0 each step), unused.
    const float* br  = (const float*)d_in[4];  // b_rnn
    const float* Wo  = (const float*)d_in[5];  // W_out
    const float* bo  = (const float*)d_in[6];  // b_out
    float* out = (float*)d_out;

    const int threads = (Bn / 2) * 4;  // 131072: 4 lanes per row-pair
    deform_kernel<<<dim3(threads / 256), dim3(256), 0, stream>>>(cp, fin, Wr, br, Wo, bo, out);
}